// Round 6
// baseline (591.224 us; speedup 1.0000x reference)
//
#include <hip/hip_runtime.h>

#define DEPTH 18
#define EMB 128
#define HID 256
#define VAL 32
#define N_LEAVES (1 << DEPTH)
#define LEAF_START (N_LEAVES - 1)

typedef _Float16 half8 __attribute__((ext_vector_type(8)));
typedef _Float16 half4 __attribute__((ext_vector_type(4)));
typedef float f32x4 __attribute__((ext_vector_type(4)));

__device__ __forceinline__ float lrelu(float x) { return x > 0.f ? x : 0.01f * x; }

// ---------------------------------------------------------------------------
// Prep: swizzle W1 (256x256), W2 (256x128), We (32x128) into fp16 MFMA
// A-fragment order for the TRANSPOSED GEMMs (A = W^T, m = output col,
// k = contraction dim). Emits hi (f16 rounding) and lo (residual) frags.
// Frag lane layout (16x16x32): lane holds A[m = lane&15][k = (lane>>4)*8 + jj].
// We has k-depth 32 = exactly one MFMA step -> 8 col-tile frags.
// ---------------------------------------------------------------------------
__global__ __launch_bounds__(256) void prep_weights(
    const float* __restrict__ W1, const float* __restrict__ W2,
    const float* __restrict__ We,
    _Float16* __restrict__ W1f, _Float16* __restrict__ W2f,
    _Float16* __restrict__ W1l, _Float16* __restrict__ W2l,
    _Float16* __restrict__ Wef, _Float16* __restrict__ Wel)
{
    const int gid = blockIdx.x * 256 + threadIdx.x;   // 12800 total
    const int lane = gid & 63;
    const int nn = lane & 15, q = lane >> 4;
    if (gid < 8192) {
        const int f = gid >> 6, kb = f >> 4, jt = f & 15;
        half8 vh, vl;
#pragma unroll
        for (int jj = 0; jj < 8; ++jj) {
            float x = W1[(kb * 32 + q * 8 + jj) * HID + jt * 16 + nn];
            _Float16 h = (_Float16)x;
            vh[jj] = h;
            vl[jj] = (_Float16)(x - (float)h);
        }
        *((half8*)W1f + gid) = vh;
        *((half8*)W1l + gid) = vl;
    } else if (gid < 12288) {
        const int g = gid - 8192;
        const int f = g >> 6, kb = f >> 3, ct = f & 7;
        half8 vh, vl;
#pragma unroll
        for (int jj = 0; jj < 8; ++jj) {
            float x = W2[(kb * 32 + q * 8 + jj) * EMB + ct * 16 + nn];
            _Float16 h = (_Float16)x;
            vh[jj] = h;
            vl[jj] = (_Float16)(x - (float)h);
        }
        *((half8*)W2f + g) = vh;
        *((half8*)W2l + g) = vl;
    } else {
        const int g = gid - 12288;          // 0..511
        const int ct = g >> 6;              // col tile 0..7
        half8 vh, vl;
#pragma unroll
        for (int jj = 0; jj < 8; ++jj) {
            float x = We[(q * 8 + jj) * EMB + ct * 16 + nn];
            _Float16 h = (_Float16)x;
            vh[jj] = h;
            vl[jj] = (_Float16)(x - (float)h);
        }
        *((half8*)Wef + g) = vh;
        *((half8*)Wel + g) = vl;
    }
}

// ---------------------------------------------------------------------------
// Strip compute: the post-stage portion of a 64-parent-row strip (8 waves,
// wave w owns W1 hid tiles {2w,2w+1} and W2 out-col tile w, register-resident).
// Barrier placement identical to round 4/5: sync (Xs ready) -> GEMM1 -> epi1
// -> sync (Hs ready) -> GEMM2 -> epi2 -> sync (stores retired before any
// dependent stage).
// ---------------------------------------------------------------------------
__device__ __forceinline__ void strip_compute(
    const half8 (&w1)[8][2], const half8 (&w2)[8],
    const f32x4 (&bb1)[2], const f32x4 bb2,
    float* __restrict__ embs, int p0, int r0,
    _Float16 (&Xs)[64][264], _Float16 (&Hs)[64][264],
    int w, int nl, int q)
{
    __syncthreads();                        // Xs ready

    // ---- GEMM1': H^T = W1^T @ X^T ----
    f32x4 d1[4][2];
#pragma unroll
    for (int s = 0; s < 4; ++s) { d1[s][0] = bb1[0]; d1[s][1] = bb1[1]; }
#pragma unroll
    for (int kb = 0; kb < 8; ++kb) {
#pragma unroll
        for (int s = 0; s < 4; ++s) {
            half8 x = *(const half8*)&Xs[s * 16 + nl][kb * 32 + q * 8];
            d1[s][0] = __builtin_amdgcn_mfma_f32_16x16x32_f16(w1[kb][0], x, d1[s][0], 0, 0, 0);
            d1[s][1] = __builtin_amdgcn_mfma_f32_16x16x32_f16(w1[kb][1], x, d1[s][1], 0, 0, 0);
        }
    }
    // ---- epilogue 1: lrelu -> f16 -> Hs (cross-wave exchange) ----
#pragma unroll
    for (int s = 0; s < 4; ++s) {
#pragma unroll
        for (int j = 0; j < 2; ++j) {
            half4 h;
#pragma unroll
            for (int r = 0; r < 4; ++r) {
                float x = d1[s][j][r];
                h[r] = (_Float16)(x > 0.f ? x : 0.01f * x);
            }
            *(half4*)&Hs[s * 16 + nl][(2 * w + j) * 16 + q * 4] = h;
        }
    }
    __syncthreads();                        // Hs ready

    // ---- GEMM2': O^T = W2^T @ H^T ----
    f32x4 d2[4];
#pragma unroll
    for (int s = 0; s < 4; ++s) d2[s] = bb2;
#pragma unroll
    for (int kb = 0; kb < 8; ++kb) {
#pragma unroll
        for (int s = 0; s < 4; ++s) {
            half8 h = *(const half8*)&Hs[s * 16 + nl][kb * 32 + q * 8];
            d2[s] = __builtin_amdgcn_mfma_f32_16x16x32_f16(w2[kb], h, d2[s], 0, 0, 0);
        }
    }
    // ---- epilogue 2: lrelu -> fp32 embs ----
    float* obase = embs + ((size_t)p0 + r0) * EMB;
#pragma unroll
    for (int s = 0; s < 4; ++s) {
        f32x4 o;
#pragma unroll
        for (int r = 0; r < 4; ++r) {
            float x = d2[s][r];
            o[r] = x > 0.f ? x : 0.01f * x;
        }
        *(f32x4*)(obase + (s * 16 + nl) * EMB + w * 16 + q * 4) = o;
    }
    __syncthreads();   // stores visible before next strip/level stages
}

// Classic global-read stage: children rows [2*r0, 2*r0+128) -> f16 Xs.
__device__ __forceinline__ void stage_global(
    const float* __restrict__ embs, int p0, int r0,
    _Float16 (&Xs)[64][264], int tid)
{
    const float4* src = (const float4*)(embs + ((size_t)(2 * p0 + 1) + 2 * (size_t)r0) * EMB);
#pragma unroll
    for (int i = 0; i < 8; ++i) {
        const int f = i * 512 + tid;       // 0..4095 float4s
        float4 v = src[f];
        half4 h;
        h[0] = (_Float16)v.x; h[1] = (_Float16)v.y;
        h[2] = (_Float16)v.z; h[3] = (_Float16)v.w;
        *(half4*)&Xs[f >> 6][(f & 63) * 4] = h;
    }
}

__device__ __forceinline__ void strip64(
    const half8 (&w1)[8][2], const half8 (&w2)[8],
    const f32x4 (&bb1)[2], const f32x4 bb2,
    float* __restrict__ embs, int p0, int r0,
    _Float16 (&Xs)[64][264], _Float16 (&Hs)[64][264],
    int tid, int w, int nl, int q)
{
    stage_global(embs, p0, r0, Xs, tid);
    strip_compute(w1, w2, bb1, bb2, embs, p0, r0, Xs, Hs, w, nl, q);
}

// ---------------------------------------------------------------------------
// Tree ladder: leaf embedding + levels 17..9 in one launch, NO grid sync.
// NEW vs round 5: 512 blocks (2 per CU) instead of 256 (1 per CU).
// Round-5 counters: 183us at MfmaUtil 13% / HBM 24% / occupancy 22% -- both
// pipes idle because one block's serial stage->sync->GEMM chain had nothing
// to overlap with. Two resident blocks per CU overlap one block's staging
// with the other's MFMA. LDS 2x67.6KB = 135KB <= 160KB; VGPR must stay <=128
// for 16 waves/CU -> __launch_bounds__(512, 4) (was 120 at round 5).
// Block b owns level-l rows [R*b, R*b+R), R = 1<<(l-9): self-contained
// subtree down to l=9 (1 row/block). Per-block chain: 4+2+1 strips + 6
// small-level tiles (was 15 strips + 6). mid_ladder picks up l=8 now.
// MFMA sequence per real output element is bit-identical to round 5.
// ---------------------------------------------------------------------------
__global__ __launch_bounds__(512, 4) void tree_ladder(
    const _Float16* __restrict__ W1f, const _Float16* __restrict__ W2f,
    const _Float16* __restrict__ Wef, const _Float16* __restrict__ Wel,
    const float* __restrict__ lv, const float* __restrict__ be,
    const float* __restrict__ b1, const float* __restrict__ b2,
    float* __restrict__ embs)
{
    __shared__ alignas(16) _Float16 Xs[64][264];   // 33792 B
    __shared__ alignas(16) _Float16 Hs[64][264];   // 33792 B

    const int tid  = threadIdx.x;
    const int w    = tid >> 6;        // 0..7
    const int lane = tid & 63;
    const int nl   = lane & 15;
    const int q    = lane >> 4;
    const int b    = blockIdx.x;      // 0..511 subtree id

    // ---- one-time weight preload into registers ----
    half8 w1[8][2], w2[8];
#pragma unroll
    for (int kb = 0; kb < 8; ++kb) {
#pragma unroll
        for (int j = 0; j < 2; ++j)
            w1[kb][j] = ((const half8*)W1f)[(kb * 16 + 2 * w + j) * 64 + lane];
        w2[kb] = ((const half8*)W2f)[(kb * 8 + w) * 64 + lane];
    }
    const half8 wef = ((const half8*)Wef)[w * 64 + lane];
    const half8 wel = ((const half8*)Wel)[w * 64 + lane];
    f32x4 bb1[2], bb2, bbe;
#pragma unroll
    for (int j = 0; j < 2; ++j)
        bb1[j] = *(const f32x4*)(b1 + (2 * w + j) * 16 + q * 4);
    bb2 = *(const f32x4*)(b2 + w * 16 + q * 4);
    bbe = *(const f32x4*)(be + w * 16 + q * 4);

    // ---- level 17: 4 strips, fused leaf-embed staging ----
    {
        const int p0 = (1 << 17) - 1;          // 131071
#pragma unroll 1
        for (int t = 0; t < 4; ++t) {
            const int r0 = 256 * b + t * 64;
            // stage: leaves [2*r0, 2*r0+128): E = lrelu(lv @ We + be)
#pragma unroll
            for (int tile = 0; tile < 8; ++tile) {
                const int ll = tile * 16 + nl;             // leaf local 0..127
                const float* lvr = lv + ((size_t)2 * r0 + ll) * VAL + q * 8;
                f32x4 u = *(const f32x4*)lvr;
                f32x4 v = *(const f32x4*)(lvr + 4);
                half8 xh, xl;
#pragma unroll
                for (int r = 0; r < 4; ++r) {
                    _Float16 a = (_Float16)u[r];
                    xh[r] = a; xl[r] = (_Float16)(u[r] - (float)a);
                    _Float16 g = (_Float16)v[r];
                    xh[r + 4] = g; xl[r + 4] = (_Float16)(v[r] - (float)g);
                }
                f32x4 e = bbe;
                e = __builtin_amdgcn_mfma_f32_16x16x32_f16(wef, xh, e, 0, 0, 0);
                e = __builtin_amdgcn_mfma_f32_16x16x32_f16(wef, xl, e, 0, 0, 0);
                e = __builtin_amdgcn_mfma_f32_16x16x32_f16(wel, xh, e, 0, 0, 0);
                f32x4 o;
                half4 h4;
#pragma unroll
                for (int r = 0; r < 4; ++r) {
                    float x = e[r];
                    o[r] = x > 0.f ? x : 0.01f * x;
                    h4[r] = (_Float16)o[r];
                }
                // fp32 leaf row to output
                *(f32x4*)(embs + (size_t)(LEAF_START + 2 * r0 + ll) * EMB + w * 16 + q * 4) = o;
                // f16 into Xs, parent-pair layout: X[parent][childhalf*128 + col]
                *(half4*)&Xs[ll >> 1][(ll & 1) * 128 + w * 16 + q * 4] = h4;
            }
            strip_compute(w1, w2, bb1, bb2, embs, p0, r0, Xs, Hs, w, nl, q);
        }
    }

    // ---- levels 16..9 ----
#pragma unroll 1
    for (int l = 16; l >= 9; --l) {
        const int p0 = (1 << l) - 1;
        const int R  = 1 << (l - 9);           // rows per block at this level
        const int row0 = R * b;

        if (R >= 64) {
#pragma unroll 1
            for (int t = 0; t < (R >> 6); ++t)
                strip64(w1, w2, bb1, bb2, embs, p0, row0 + t * 64,
                        Xs, Hs, tid, w, nl, q);
        } else {
            const int ns = (R > 16) ? 2 : 1;   // 16-row tiles (R=32 -> 2)

            // ---- GEMM1': per-lane global X (same-CU L1/L2), hi-only f16 ----
            f32x4 d1[2][2];
#pragma unroll
            for (int s = 0; s < 2; ++s) { d1[s][0] = bb1[0]; d1[s][1] = bb1[1]; }
#pragma unroll
            for (int kb = 0; kb < 8; ++kb) {
#pragma unroll
                for (int s = 0; s < 2; ++s) {
                    if (s >= ns) break;
                    const int row = row0 + s * 16 + nl;   // may be garbage (>=R)
                    const float* Xr = embs + (size_t)(2 * (p0 + row) + 1) * EMB
                                    + kb * 32 + q * 8;
                    f32x4 u = *(const f32x4*)Xr;
                    f32x4 v = *(const f32x4*)(Xr + 4);
                    half8 x;
#pragma unroll
                    for (int r = 0; r < 4; ++r) {
                        x[r]     = (_Float16)u[r];
                        x[r + 4] = (_Float16)v[r];
                    }
                    d1[s][0] = __builtin_amdgcn_mfma_f32_16x16x32_f16(w1[kb][0], x, d1[s][0], 0, 0, 0);
                    d1[s][1] = __builtin_amdgcn_mfma_f32_16x16x32_f16(w1[kb][1], x, d1[s][1], 0, 0, 0);
                }
            }
            // ---- epilogue 1 (preceded by a barrier in all paths -> safe) ----
#pragma unroll
            for (int s = 0; s < 2; ++s) {
                if (s >= ns) break;
#pragma unroll
                for (int j = 0; j < 2; ++j) {
                    half4 h;
#pragma unroll
                    for (int r = 0; r < 4; ++r) {
                        float x = d1[s][j][r];
                        h[r] = (_Float16)(x > 0.f ? x : 0.01f * x);
                    }
                    *(half4*)&Hs[s * 16 + nl][(2 * w + j) * 16 + q * 4] = h;
                }
            }
            __syncthreads();                    // Hs ready

            // ---- GEMM2' ----
            f32x4 d2[2];
#pragma unroll
            for (int s = 0; s < 2; ++s) d2[s] = bb2;
#pragma unroll
            for (int kb = 0; kb < 8; ++kb) {
#pragma unroll
                for (int s = 0; s < 2; ++s) {
                    if (s >= ns) break;
                    half8 h = *(const half8*)&Hs[s * 16 + nl][kb * 32 + q * 8];
                    d2[s] = __builtin_amdgcn_mfma_f32_16x16x32_f16(w2[kb], h, d2[s], 0, 0, 0);
                }
            }
            // ---- epilogue 2: guarded fp32 writes (garbage rows dropped) ----
#pragma unroll
            for (int s = 0; s < 2; ++s) {
                if (s >= ns) break;
                const int idx = s * 16 + nl;
                f32x4 o;
#pragma unroll
                for (int r = 0; r < 4; ++r) {
                    float x = d2[s][r];
                    o[r] = x > 0.f ? x : 0.01f * x;
                }
                if (idx < R)
                    *(f32x4*)(embs + (size_t)(p0 + row0 + idx) * EMB + w * 16 + q * 4) = o;
            }
            __syncthreads();                    // level complete (L1/L2-visible)
        }
    }
}

// ---------------------------------------------------------------------------
// Mid ladder: levels 8,7,6 (one block, seven strip64 calls). Children of
// level 8 come from tree_ladder (cross-kernel dispatch boundary -> visible);
// deeper levels come from this block's own strips (barrier'd).
// ---------------------------------------------------------------------------
__global__ __launch_bounds__(512) void mid_ladder(
    const _Float16* __restrict__ W1f, const _Float16* __restrict__ W2f,
    const float* __restrict__ b1, const float* __restrict__ b2,
    float* __restrict__ embs)
{
    __shared__ alignas(16) _Float16 Xs[64][264];
    __shared__ alignas(16) _Float16 Hs[64][264];

    const int tid  = threadIdx.x;
    const int w    = tid >> 6;
    const int lane = tid & 63;
    const int nl   = lane & 15;
    const int q    = lane >> 4;

    half8 w1[8][2], w2[8];
#pragma unroll
    for (int kb = 0; kb < 8; ++kb) {
#pragma unroll
        for (int j = 0; j < 2; ++j)
            w1[kb][j] = ((const half8*)W1f)[(kb * 16 + 2 * w + j) * 64 + lane];
        w2[kb] = ((const half8*)W2f)[(kb * 8 + w) * 64 + lane];
    }
    f32x4 bb1[2], bb2;
#pragma unroll
    for (int j = 0; j < 2; ++j)
        bb1[j] = *(const f32x4*)(b1 + (2 * w + j) * 16 + q * 4);
    bb2 = *(const f32x4*)(b2 + w * 16 + q * 4);

    strip64(w1, w2, bb1, bb2, embs, 255,   0, Xs, Hs, tid, w, nl, q);  // l=8
    strip64(w1, w2, bb1, bb2, embs, 255,  64, Xs, Hs, tid, w, nl, q);
    strip64(w1, w2, bb1, bb2, embs, 255, 128, Xs, Hs, tid, w, nl, q);
    strip64(w1, w2, bb1, bb2, embs, 255, 192, Xs, Hs, tid, w, nl, q);
    strip64(w1, w2, bb1, bb2, embs, 127,   0, Xs, Hs, tid, w, nl, q);  // l=7
    strip64(w1, w2, bb1, bb2, embs, 127,  64, Xs, Hs, tid, w, nl, q);
    strip64(w1, w2, bb1, bb2, embs,  63,   0, Xs, Hs, tid, w, nl, q);  // l=6
}

// ---------------------------------------------------------------------------
// Levels 5..0 (63 nodes) fused in ONE 8-wave block, split-precision f16 MFMA
// (acc += xh*wh + xl*wh + xh*wl -> ~fp32 accuracy, rel err ~2^-22).
// Weights REGISTER-RESIDENT (hi+lo), loaded once. Activations ping-pong in
// LDS as f16 hi/lo pairs. Unchanged since round 2 (measured ~40 us).
// ---------------------------------------------------------------------------
__global__ __launch_bounds__(512, 2) void tail_levels(
    const _Float16* __restrict__ W1f, const _Float16* __restrict__ W1l,
    const _Float16* __restrict__ W2f, const _Float16* __restrict__ W2l,
    const float* __restrict__ b1, const float* __restrict__ b2,
    float* __restrict__ embs)
{
    __shared__ alignas(16) _Float16 Hsh[32][264];      // 16896 B
    __shared__ alignas(16) _Float16 Hsl[32][264];      // 16896 B
    __shared__ alignas(16) _Float16 Obh[2][16][136];   //  8704 B
    __shared__ alignas(16) _Float16 Obl[2][16][136];   //  8704 B   (51.2 KB)

    const int tid  = threadIdx.x;
    const int w    = tid >> 6;        // 0..7
    const int lane = tid & 63;
    const int nl   = lane & 15;
    const int q    = lane >> 4;

    // ---- one-time weight preload into registers (static indexing only) ----
    half8 w1h[8][2], w1l[8][2], w2h[8], w2l[8];
#pragma unroll
    for (int kb = 0; kb < 8; ++kb) {
#pragma unroll
        for (int j = 0; j < 2; ++j) {
            const int f = kb * 16 + (2 * w + j);
            w1h[kb][j] = ((const half8*)W1f)[f * 64 + lane];
            w1l[kb][j] = ((const half8*)W1l)[f * 64 + lane];
        }
        const int g = kb * 8 + w;
        w2h[kb] = ((const half8*)W2f)[g * 64 + lane];
        w2l[kb] = ((const half8*)W2l)[g * 64 + lane];
    }

#pragma unroll 1
    for (int l = 5; l >= 0; --l) {
        const int p0 = (1 << l) - 1, n = 1 << l;
        const int ns = (l == 5) ? 2 : 1;     // strips of 16 rows (uniform)

        // ---- GEMM1': H^T = W1^T @ X^T, bias-init, split f16 ----
        f32x4 d1[2][2];
#pragma unroll
        for (int s = 0; s < 2; ++s)
#pragma unroll
            for (int j = 0; j < 2; ++j)
                d1[s][j] = *(const f32x4*)(b1 + (2 * w + j) * 16 + q * 4);

#pragma unroll
        for (int kb = 0; kb < 8; ++kb) {
            const int k0  = kb * 32 + q * 8;        // 0..255, 8-aligned
            const int hi  = kb >> 2;                // which child half
            const int col = (kb & 3) * 32 + q * 8;  // col within child
#pragma unroll
            for (int s = 0; s < 2; ++s) {
                if (s >= ns) break;
                half8 xh, xl;
                if (l == 5) {
                    const int row = s * 16 + nl;
                    const float* Xr = embs + (size_t)(63 + 2 * row) * EMB + k0;
                    f32x4 u = *(const f32x4*)Xr;
                    f32x4 v = *(const f32x4*)(Xr + 4);
#pragma unroll
                    for (int r = 0; r < 4; ++r) {
                        _Float16 a = (_Float16)u[r];
                        xh[r] = a; xl[r] = (_Float16)(u[r] - (float)a);
                        _Float16 b = (_Float16)v[r];
                        xh[r + 4] = b; xl[r + 4] = (_Float16)(v[r] - (float)b);
                    }
                } else {
                    // child = (2*row + hi) & 31 = 2*nl + hi  (independent of s)
                    xh = *(const half8*)&Obh[hi][nl][col];
                    xl = *(const half8*)&Obl[hi][nl][col];
                }
#pragma unroll
                for (int j = 0; j < 2; ++j) {
                    d1[s][j] = __builtin_amdgcn_mfma_f32_16x16x32_f16(w1h[kb][j], xh, d1[s][j], 0, 0, 0);
                    d1[s][j] = __builtin_amdgcn_mfma_f32_16x16x32_f16(w1h[kb][j], xl, d1[s][j], 0, 0, 0);
                    d1[s][j] = __builtin_amdgcn_mfma_f32_16x16x32_f16(w1l[kb][j], xh, d1[s][j], 0, 0, 0);
                }
            }
        }

        // ---- epilogue 1: lrelu, hi/lo f16, store H to LDS (cross-wave) ----
#pragma unroll
        for (int s = 0; s < 2; ++s) {
            if (s >= ns) break;
            const int row = s * 16 + nl;
#pragma unroll
            for (int j = 0; j < 2; ++j) {
                half4 hh4, hl4;
#pragma unroll
                for (int r = 0; r < 4; ++r) {
                    float x = d1[s][j][r];
                    x = x > 0.f ? x : 0.01f * x;
                    _Float16 a = (_Float16)x;
                    hh4[r] = a; hl4[r] = (_Float16)(x - (float)a);
                }
                const int cf = (2 * w + j) * 16 + q * 4;
                *(half4*)&Hsh[row][cf] = hh4;
                *(half4*)&Hsl[row][cf] = hl4;
            }
        }
        __syncthreads();

        // ---- GEMM2': O^T = W2^T @ H^T, split f16 ----
        f32x4 d2[2];
#pragma unroll
        for (int s = 0; s < 2; ++s)
            d2[s] = *(const f32x4*)(b2 + w * 16 + q * 4);

#pragma unroll
        for (int kb = 0; kb < 8; ++kb) {
#pragma unroll
            for (int s = 0; s < 2; ++s) {
                if (s >= ns) break;
                const int row = s * 16 + nl;
                half8 hh = *(const half8*)&Hsh[row][kb * 32 + q * 8];
                half8 hl = *(const half8*)&Hsl[row][kb * 32 + q * 8];
                d2[s] = __builtin_amdgcn_mfma_f32_16x16x32_f16(w2h[kb], hh, d2[s], 0, 0, 0);
                d2[s] = __builtin_amdgcn_mfma_f32_16x16x32_f16(w2h[kb], hl, d2[s], 0, 0, 0);
                d2[s] = __builtin_amdgcn_mfma_f32_16x16x32_f16(w2l[kb], hh, d2[s], 0, 0, 0);
            }
        }

        // ---- epilogue 2: lrelu; O to parity-split LDS + global for row<n ----
#pragma unroll
        for (int s = 0; s < 2; ++s) {
            if (s >= ns) break;
            const int row = s * 16 + nl;
            f32x4 o;
#pragma unroll
            for (int r = 0; r < 4; ++r) { float x = d2[s][r]; o[r] = x > 0.f ? x : 0.01f * x; }
            half4 oh4, ol4;
#pragma unroll
            for (int r = 0; r < 4; ++r) {
                _Float16 a = (_Float16)o[r];
                oh4[r] = a; ol4[r] = (_Float16)(o[r] - (float)a);
            }
            const int cf = w * 16 + q * 4;
            *(half4*)&Obh[row & 1][row >> 1][cf] = oh4;
            *(half4*)&Obl[row & 1][row >> 1][cf] = ol4;
            if (row < n)
                *(f32x4*)(embs + (size_t)(p0 + row) * EMB + cf) = o;
        }
        __syncthreads();
    }
}

// ---------------------------------------------------------------------------
extern "C" void kernel_launch(void* const* d_in, const int* in_sizes, int n_in,
                              void* d_out, int out_size, void* d_ws, size_t ws_size,
                              hipStream_t stream)
{
    const float* lv = (const float*)d_in[0];
    const float* We = (const float*)d_in[1];
    const float* be = (const float*)d_in[2];
    const float* W1 = (const float*)d_in[3];
    const float* b1 = (const float*)d_in[4];
    const float* W2 = (const float*)d_in[5];
    const float* b2 = (const float*)d_in[6];
    float* embs = (float*)d_out;

    _Float16* W1f = (_Float16*)d_ws;            // 65536 f16 = 128 KB
    _Float16* W2f = W1f + 65536;                // 32768 f16 =  64 KB
    _Float16* W1l = W2f + 32768;                // 65536 f16 = 128 KB
    _Float16* W2l = W1l + 65536;                // 32768 f16 =  64 KB
    _Float16* Wef = W2l + 32768;                //  4096 f16 =   8 KB
    _Float16* Wel = Wef + 4096;                 //  4096 f16 =   8 KB  (400 KB)

    prep_weights<<<50, 256, 0, stream>>>(W1, W2, We, W1f, W2f, W1l, W2l, Wef, Wel);
    tree_ladder<<<512, 512, 0, stream>>>(W1f, W2f, Wef, Wel, lv, be, b1, b2, embs);
    mid_ladder<<<1, 512, 0, stream>>>(W1f, W2f, b1, b2, embs);
    tail_levels<<<1, 512, 0, stream>>>(W1f, W1l, W2f, W2l, b1, b2, embs);
}

// Round 7
// 509.389 us; speedup vs baseline: 1.1607x; 1.1607x over previous
//
#include <hip/hip_runtime.h>

#define DEPTH 18
#define EMB 128
#define HID 256
#define VAL 32
#define N_LEAVES (1 << DEPTH)
#define LEAF_START (N_LEAVES - 1)

typedef _Float16 half8 __attribute__((ext_vector_type(8)));
typedef _Float16 half4 __attribute__((ext_vector_type(4)));
typedef float f32x4 __attribute__((ext_vector_type(4)));

__device__ __forceinline__ float lrelu(float x) { return x > 0.f ? x : 0.01f * x; }

// ---------------------------------------------------------------------------
// Prep: swizzle W1 (256x256), W2 (256x128), We (32x128) into fp16 MFMA
// A-fragment order for the TRANSPOSED GEMMs (A = W^T, m = output col,
// k = contraction dim). Emits hi (f16 rounding) and lo (residual) frags.
// Frag lane layout (16x16x32): lane holds A[m = lane&15][k = (lane>>4)*8 + jj].
// We has k-depth 32 = exactly one MFMA step -> 8 col-tile frags.
// ---------------------------------------------------------------------------
__global__ __launch_bounds__(256) void prep_weights(
    const float* __restrict__ W1, const float* __restrict__ W2,
    const float* __restrict__ We,
    _Float16* __restrict__ W1f, _Float16* __restrict__ W2f,
    _Float16* __restrict__ W1l, _Float16* __restrict__ W2l,
    _Float16* __restrict__ Wef, _Float16* __restrict__ Wel)
{
    const int gid = blockIdx.x * 256 + threadIdx.x;   // 12800 total
    const int lane = gid & 63;
    const int nn = lane & 15, q = lane >> 4;
    if (gid < 8192) {
        const int f = gid >> 6, kb = f >> 4, jt = f & 15;
        half8 vh, vl;
#pragma unroll
        for (int jj = 0; jj < 8; ++jj) {
            float x = W1[(kb * 32 + q * 8 + jj) * HID + jt * 16 + nn];
            _Float16 h = (_Float16)x;
            vh[jj] = h;
            vl[jj] = (_Float16)(x - (float)h);
        }
        *((half8*)W1f + gid) = vh;
        *((half8*)W1l + gid) = vl;
    } else if (gid < 12288) {
        const int g = gid - 8192;
        const int f = g >> 6, kb = f >> 3, ct = f & 7;
        half8 vh, vl;
#pragma unroll
        for (int jj = 0; jj < 8; ++jj) {
            float x = W2[(kb * 32 + q * 8 + jj) * EMB + ct * 16 + nn];
            _Float16 h = (_Float16)x;
            vh[jj] = h;
            vl[jj] = (_Float16)(x - (float)h);
        }
        *((half8*)W2f + g) = vh;
        *((half8*)W2l + g) = vl;
    } else {
        const int g = gid - 12288;          // 0..511
        const int ct = g >> 6;              // col tile 0..7
        half8 vh, vl;
#pragma unroll
        for (int jj = 0; jj < 8; ++jj) {
            float x = We[(q * 8 + jj) * EMB + ct * 16 + nn];
            _Float16 h = (_Float16)x;
            vh[jj] = h;
            vl[jj] = (_Float16)(x - (float)h);
        }
        *((half8*)Wef + g) = vh;
        *((half8*)Wel + g) = vl;
    }
}

// ---------------------------------------------------------------------------
// Strip compute: the post-stage portion of a 64-parent-row strip (8 waves,
// wave w owns W1 hid tiles {2w,2w+1} and W2 out-col tile w, register-resident).
// Barrier placement identical to round 4/5: sync (Xs ready) -> GEMM1 -> epi1
// -> sync (Hs ready) -> GEMM2 -> epi2 -> sync (stores retired before any
// dependent stage).
// ---------------------------------------------------------------------------
__device__ __forceinline__ void strip_compute(
    const half8 (&w1)[8][2], const half8 (&w2)[8],
    const f32x4 (&bb1)[2], const f32x4 bb2,
    float* __restrict__ embs, int p0, int r0,
    _Float16 (&Xs)[64][264], _Float16 (&Hs)[64][264],
    int w, int nl, int q)
{
    __syncthreads();                        // Xs ready

    // ---- GEMM1': H^T = W1^T @ X^T ----
    f32x4 d1[4][2];
#pragma unroll
    for (int s = 0; s < 4; ++s) { d1[s][0] = bb1[0]; d1[s][1] = bb1[1]; }
#pragma unroll
    for (int kb = 0; kb < 8; ++kb) {
#pragma unroll
        for (int s = 0; s < 4; ++s) {
            half8 x = *(const half8*)&Xs[s * 16 + nl][kb * 32 + q * 8];
            d1[s][0] = __builtin_amdgcn_mfma_f32_16x16x32_f16(w1[kb][0], x, d1[s][0], 0, 0, 0);
            d1[s][1] = __builtin_amdgcn_mfma_f32_16x16x32_f16(w1[kb][1], x, d1[s][1], 0, 0, 0);
        }
    }
    // ---- epilogue 1: lrelu -> f16 -> Hs (cross-wave exchange) ----
#pragma unroll
    for (int s = 0; s < 4; ++s) {
#pragma unroll
        for (int j = 0; j < 2; ++j) {
            half4 h;
#pragma unroll
            for (int r = 0; r < 4; ++r) {
                float x = d1[s][j][r];
                h[r] = (_Float16)(x > 0.f ? x : 0.01f * x);
            }
            *(half4*)&Hs[s * 16 + nl][(2 * w + j) * 16 + q * 4] = h;
        }
    }
    __syncthreads();                        // Hs ready

    // ---- GEMM2': O^T = W2^T @ H^T ----
    f32x4 d2[4];
#pragma unroll
    for (int s = 0; s < 4; ++s) d2[s] = bb2;
#pragma unroll
    for (int kb = 0; kb < 8; ++kb) {
#pragma unroll
        for (int s = 0; s < 4; ++s) {
            half8 h = *(const half8*)&Hs[s * 16 + nl][kb * 32 + q * 8];
            d2[s] = __builtin_amdgcn_mfma_f32_16x16x32_f16(w2[kb], h, d2[s], 0, 0, 0);
        }
    }
    // ---- epilogue 2: lrelu -> fp32 embs ----
    float* obase = embs + ((size_t)p0 + r0) * EMB;
#pragma unroll
    for (int s = 0; s < 4; ++s) {
        f32x4 o;
#pragma unroll
        for (int r = 0; r < 4; ++r) {
            float x = d2[s][r];
            o[r] = x > 0.f ? x : 0.01f * x;
        }
        *(f32x4*)(obase + (s * 16 + nl) * EMB + w * 16 + q * 4) = o;
    }
    __syncthreads();   // stores visible before next strip/level stages
}

// Classic global-read stage: children rows [2*r0, 2*r0+128) -> f16 Xs.
__device__ __forceinline__ void stage_global(
    const float* __restrict__ embs, int p0, int r0,
    _Float16 (&Xs)[64][264], int tid)
{
    const float4* src = (const float4*)(embs + ((size_t)(2 * p0 + 1) + 2 * (size_t)r0) * EMB);
#pragma unroll
    for (int i = 0; i < 8; ++i) {
        const int f = i * 512 + tid;       // 0..4095 float4s
        float4 v = src[f];
        half4 h;
        h[0] = (_Float16)v.x; h[1] = (_Float16)v.y;
        h[2] = (_Float16)v.z; h[3] = (_Float16)v.w;
        *(half4*)&Xs[f >> 6][(f & 63) * 4] = h;
    }
}

__device__ __forceinline__ void strip64(
    const half8 (&w1)[8][2], const half8 (&w2)[8],
    const f32x4 (&bb1)[2], const f32x4 bb2,
    float* __restrict__ embs, int p0, int r0,
    _Float16 (&Xs)[64][264], _Float16 (&Hs)[64][264],
    int tid, int w, int nl, int q)
{
    stage_global(embs, p0, r0, Xs, tid);
    strip_compute(w1, w2, bb1, bb2, embs, p0, r0, Xs, Hs, w, nl, q);
}

// ---------------------------------------------------------------------------
// Tree ladder: leaf embedding + levels 17..9 in one launch, NO grid sync.
// 512 blocks (2 per CU), block b owns level-l rows [R*b, R*b+R), R=1<<(l-9).
//
// ROUND-7 FIX: plain __launch_bounds__(512) -- NO min-waves arg. Round 6's
// (512,4) forced the allocator to spill the 96-VGPR register-resident weight
// bank to scratch (VGPR 120->64, +478 MB HBM spill traffic, 183->303us).
// The round-5 body compiled to 120 VGPR <= 128 naturally, which is exactly
// the 2-blocks/CU threshold; grid=512 alone delivers the overlap.
// MFMA sequence per real output element is bit-identical to rounds 4/5/6.
// ---------------------------------------------------------------------------
__global__ __launch_bounds__(512) void tree_ladder(
    const _Float16* __restrict__ W1f, const _Float16* __restrict__ W2f,
    const _Float16* __restrict__ Wef, const _Float16* __restrict__ Wel,
    const float* __restrict__ lv, const float* __restrict__ be,
    const float* __restrict__ b1, const float* __restrict__ b2,
    float* __restrict__ embs)
{
    __shared__ alignas(16) _Float16 Xs[64][264];   // 33792 B
    __shared__ alignas(16) _Float16 Hs[64][264];   // 33792 B  (67.6 KB: 2/CU)

    const int tid  = threadIdx.x;
    const int w    = tid >> 6;        // 0..7
    const int lane = tid & 63;
    const int nl   = lane & 15;
    const int q    = lane >> 4;
    const int b    = blockIdx.x;      // 0..511 subtree id

    // ---- one-time weight preload into registers ----
    half8 w1[8][2], w2[8];
#pragma unroll
    for (int kb = 0; kb < 8; ++kb) {
#pragma unroll
        for (int j = 0; j < 2; ++j)
            w1[kb][j] = ((const half8*)W1f)[(kb * 16 + 2 * w + j) * 64 + lane];
        w2[kb] = ((const half8*)W2f)[(kb * 8 + w) * 64 + lane];
    }
    const half8 wef = ((const half8*)Wef)[w * 64 + lane];
    const half8 wel = ((const half8*)Wel)[w * 64 + lane];
    f32x4 bb1[2], bb2, bbe;
#pragma unroll
    for (int j = 0; j < 2; ++j)
        bb1[j] = *(const f32x4*)(b1 + (2 * w + j) * 16 + q * 4);
    bb2 = *(const f32x4*)(b2 + w * 16 + q * 4);
    bbe = *(const f32x4*)(be + w * 16 + q * 4);

    // ---- level 17: 4 strips, fused leaf-embed staging ----
    {
        const int p0 = (1 << 17) - 1;          // 131071
#pragma unroll 1
        for (int t = 0; t < 4; ++t) {
            const int r0 = 256 * b + t * 64;
            // stage: leaves [2*r0, 2*r0+128): E = lrelu(lv @ We + be)
#pragma unroll
            for (int tile = 0; tile < 8; ++tile) {
                const int ll = tile * 16 + nl;             // leaf local 0..127
                const float* lvr = lv + ((size_t)2 * r0 + ll) * VAL + q * 8;
                f32x4 u = *(const f32x4*)lvr;
                f32x4 v = *(const f32x4*)(lvr + 4);
                half8 xh, xl;
#pragma unroll
                for (int r = 0; r < 4; ++r) {
                    _Float16 a = (_Float16)u[r];
                    xh[r] = a; xl[r] = (_Float16)(u[r] - (float)a);
                    _Float16 g = (_Float16)v[r];
                    xh[r + 4] = g; xl[r + 4] = (_Float16)(v[r] - (float)g);
                }
                f32x4 e = bbe;
                e = __builtin_amdgcn_mfma_f32_16x16x32_f16(wef, xh, e, 0, 0, 0);
                e = __builtin_amdgcn_mfma_f32_16x16x32_f16(wef, xl, e, 0, 0, 0);
                e = __builtin_amdgcn_mfma_f32_16x16x32_f16(wel, xh, e, 0, 0, 0);
                f32x4 o;
                half4 h4;
#pragma unroll
                for (int r = 0; r < 4; ++r) {
                    float x = e[r];
                    o[r] = x > 0.f ? x : 0.01f * x;
                    h4[r] = (_Float16)o[r];
                }
                // fp32 leaf row to output
                *(f32x4*)(embs + (size_t)(LEAF_START + 2 * r0 + ll) * EMB + w * 16 + q * 4) = o;
                // f16 into Xs, parent-pair layout: X[parent][childhalf*128 + col]
                *(half4*)&Xs[ll >> 1][(ll & 1) * 128 + w * 16 + q * 4] = h4;
            }
            strip_compute(w1, w2, bb1, bb2, embs, p0, r0, Xs, Hs, w, nl, q);
        }
    }

    // ---- levels 16..9 ----
#pragma unroll 1
    for (int l = 16; l >= 9; --l) {
        const int p0 = (1 << l) - 1;
        const int R  = 1 << (l - 9);           // rows per block at this level
        const int row0 = R * b;

        if (R >= 64) {
#pragma unroll 1
            for (int t = 0; t < (R >> 6); ++t)
                strip64(w1, w2, bb1, bb2, embs, p0, row0 + t * 64,
                        Xs, Hs, tid, w, nl, q);
        } else {
            const int ns = (R > 16) ? 2 : 1;   // 16-row tiles (R=32 -> 2)

            // ---- GEMM1': per-lane global X (same-CU L1/L2), hi-only f16 ----
            f32x4 d1[2][2];
#pragma unroll
            for (int s = 0; s < 2; ++s) { d1[s][0] = bb1[0]; d1[s][1] = bb1[1]; }
#pragma unroll
            for (int kb = 0; kb < 8; ++kb) {
#pragma unroll
                for (int s = 0; s < 2; ++s) {
                    if (s >= ns) break;
                    const int row = row0 + s * 16 + nl;   // may be garbage (>=R)
                    const float* Xr = embs + (size_t)(2 * (p0 + row) + 1) * EMB
                                    + kb * 32 + q * 8;
                    f32x4 u = *(const f32x4*)Xr;
                    f32x4 v = *(const f32x4*)(Xr + 4);
                    half8 x;
#pragma unroll
                    for (int r = 0; r < 4; ++r) {
                        x[r]     = (_Float16)u[r];
                        x[r + 4] = (_Float16)v[r];
                    }
                    d1[s][0] = __builtin_amdgcn_mfma_f32_16x16x32_f16(w1[kb][0], x, d1[s][0], 0, 0, 0);
                    d1[s][1] = __builtin_amdgcn_mfma_f32_16x16x32_f16(w1[kb][1], x, d1[s][1], 0, 0, 0);
                }
            }
            // ---- epilogue 1 (preceded by a barrier in all paths -> safe) ----
#pragma unroll
            for (int s = 0; s < 2; ++s) {
                if (s >= ns) break;
#pragma unroll
                for (int j = 0; j < 2; ++j) {
                    half4 h;
#pragma unroll
                    for (int r = 0; r < 4; ++r) {
                        float x = d1[s][j][r];
                        h[r] = (_Float16)(x > 0.f ? x : 0.01f * x);
                    }
                    *(half4*)&Hs[s * 16 + nl][(2 * w + j) * 16 + q * 4] = h;
                }
            }
            __syncthreads();                    // Hs ready

            // ---- GEMM2' ----
            f32x4 d2[2];
#pragma unroll
            for (int s = 0; s < 2; ++s) d2[s] = bb2;
#pragma unroll
            for (int kb = 0; kb < 8; ++kb) {
#pragma unroll
                for (int s = 0; s < 2; ++s) {
                    if (s >= ns) break;
                    half8 h = *(const half8*)&Hs[s * 16 + nl][kb * 32 + q * 8];
                    d2[s] = __builtin_amdgcn_mfma_f32_16x16x32_f16(w2[kb], h, d2[s], 0, 0, 0);
                }
            }
            // ---- epilogue 2: guarded fp32 writes (garbage rows dropped) ----
#pragma unroll
            for (int s = 0; s < 2; ++s) {
                if (s >= ns) break;
                const int idx = s * 16 + nl;
                f32x4 o;
#pragma unroll
                for (int r = 0; r < 4; ++r) {
                    float x = d2[s][r];
                    o[r] = x > 0.f ? x : 0.01f * x;
                }
                if (idx < R)
                    *(f32x4*)(embs + (size_t)(p0 + row0 + idx) * EMB + w * 16 + q * 4) = o;
            }
            __syncthreads();                    // level complete (L1/L2-visible)
        }
    }
}

// ---------------------------------------------------------------------------
// Mid ladder: levels 8,7,6 (one block, seven strip64 calls). Children of
// level 8 come from tree_ladder (cross-kernel dispatch boundary -> visible);
// deeper levels come from this block's own strips (barrier'd).
// ---------------------------------------------------------------------------
__global__ __launch_bounds__(512) void mid_ladder(
    const _Float16* __restrict__ W1f, const _Float16* __restrict__ W2f,
    const float* __restrict__ b1, const float* __restrict__ b2,
    float* __restrict__ embs)
{
    __shared__ alignas(16) _Float16 Xs[64][264];
    __shared__ alignas(16) _Float16 Hs[64][264];

    const int tid  = threadIdx.x;
    const int w    = tid >> 6;
    const int lane = tid & 63;
    const int nl   = lane & 15;
    const int q    = lane >> 4;

    half8 w1[8][2], w2[8];
#pragma unroll
    for (int kb = 0; kb < 8; ++kb) {
#pragma unroll
        for (int j = 0; j < 2; ++j)
            w1[kb][j] = ((const half8*)W1f)[(kb * 16 + 2 * w + j) * 64 + lane];
        w2[kb] = ((const half8*)W2f)[(kb * 8 + w) * 64 + lane];
    }
    f32x4 bb1[2], bb2;
#pragma unroll
    for (int j = 0; j < 2; ++j)
        bb1[j] = *(const f32x4*)(b1 + (2 * w + j) * 16 + q * 4);
    bb2 = *(const f32x4*)(b2 + w * 16 + q * 4);

    strip64(w1, w2, bb1, bb2, embs, 255,   0, Xs, Hs, tid, w, nl, q);  // l=8
    strip64(w1, w2, bb1, bb2, embs, 255,  64, Xs, Hs, tid, w, nl, q);
    strip64(w1, w2, bb1, bb2, embs, 255, 128, Xs, Hs, tid, w, nl, q);
    strip64(w1, w2, bb1, bb2, embs, 255, 192, Xs, Hs, tid, w, nl, q);
    strip64(w1, w2, bb1, bb2, embs, 127,   0, Xs, Hs, tid, w, nl, q);  // l=7
    strip64(w1, w2, bb1, bb2, embs, 127,  64, Xs, Hs, tid, w, nl, q);
    strip64(w1, w2, bb1, bb2, embs,  63,   0, Xs, Hs, tid, w, nl, q);  // l=6
}

// ---------------------------------------------------------------------------
// Levels 5..0 (63 nodes) fused in ONE 8-wave block, split-precision f16 MFMA
// (acc += xh*wh + xl*wh + xh*wl -> ~fp32 accuracy, rel err ~2^-22).
// Weights REGISTER-RESIDENT (hi+lo), loaded once. Activations ping-pong in
// LDS as f16 hi/lo pairs. Unchanged since round 2 (measured ~40 us).
// ---------------------------------------------------------------------------
__global__ __launch_bounds__(512, 2) void tail_levels(
    const _Float16* __restrict__ W1f, const _Float16* __restrict__ W1l,
    const _Float16* __restrict__ W2f, const _Float16* __restrict__ W2l,
    const float* __restrict__ b1, const float* __restrict__ b2,
    float* __restrict__ embs)
{
    __shared__ alignas(16) _Float16 Hsh[32][264];      // 16896 B
    __shared__ alignas(16) _Float16 Hsl[32][264];      // 16896 B
    __shared__ alignas(16) _Float16 Obh[2][16][136];   //  8704 B
    __shared__ alignas(16) _Float16 Obl[2][16][136];   //  8704 B   (51.2 KB)

    const int tid  = threadIdx.x;
    const int w    = tid >> 6;        // 0..7
    const int lane = tid & 63;
    const int nl   = lane & 15;
    const int q    = lane >> 4;

    // ---- one-time weight preload into registers (static indexing only) ----
    half8 w1h[8][2], w1l[8][2], w2h[8], w2l[8];
#pragma unroll
    for (int kb = 0; kb < 8; ++kb) {
#pragma unroll
        for (int j = 0; j < 2; ++j) {
            const int f = kb * 16 + (2 * w + j);
            w1h[kb][j] = ((const half8*)W1f)[f * 64 + lane];
            w1l[kb][j] = ((const half8*)W1l)[f * 64 + lane];
        }
        const int g = kb * 8 + w;
        w2h[kb] = ((const half8*)W2f)[g * 64 + lane];
        w2l[kb] = ((const half8*)W2l)[g * 64 + lane];
    }

#pragma unroll 1
    for (int l = 5; l >= 0; --l) {
        const int p0 = (1 << l) - 1, n = 1 << l;
        const int ns = (l == 5) ? 2 : 1;     // strips of 16 rows (uniform)

        // ---- GEMM1': H^T = W1^T @ X^T, bias-init, split f16 ----
        f32x4 d1[2][2];
#pragma unroll
        for (int s = 0; s < 2; ++s)
#pragma unroll
            for (int j = 0; j < 2; ++j)
                d1[s][j] = *(const f32x4*)(b1 + (2 * w + j) * 16 + q * 4);

#pragma unroll
        for (int kb = 0; kb < 8; ++kb) {
            const int k0  = kb * 32 + q * 8;        // 0..255, 8-aligned
            const int hi  = kb >> 2;                // which child half
            const int col = (kb & 3) * 32 + q * 8;  // col within child
#pragma unroll
            for (int s = 0; s < 2; ++s) {
                if (s >= ns) break;
                half8 xh, xl;
                if (l == 5) {
                    const int row = s * 16 + nl;
                    const float* Xr = embs + (size_t)(63 + 2 * row) * EMB + k0;
                    f32x4 u = *(const f32x4*)Xr;
                    f32x4 v = *(const f32x4*)(Xr + 4);
#pragma unroll
                    for (int r = 0; r < 4; ++r) {
                        _Float16 a = (_Float16)u[r];
                        xh[r] = a; xl[r] = (_Float16)(u[r] - (float)a);
                        _Float16 b = (_Float16)v[r];
                        xh[r + 4] = b; xl[r + 4] = (_Float16)(v[r] - (float)b);
                    }
                } else {
                    // child = (2*row + hi) & 31 = 2*nl + hi  (independent of s)
                    xh = *(const half8*)&Obh[hi][nl][col];
                    xl = *(const half8*)&Obl[hi][nl][col];
                }
#pragma unroll
                for (int j = 0; j < 2; ++j) {
                    d1[s][j] = __builtin_amdgcn_mfma_f32_16x16x32_f16(w1h[kb][j], xh, d1[s][j], 0, 0, 0);
                    d1[s][j] = __builtin_amdgcn_mfma_f32_16x16x32_f16(w1h[kb][j], xl, d1[s][j], 0, 0, 0);
                    d1[s][j] = __builtin_amdgcn_mfma_f32_16x16x32_f16(w1l[kb][j], xh, d1[s][j], 0, 0, 0);
                }
            }
        }

        // ---- epilogue 1: lrelu, hi/lo f16, store H to LDS (cross-wave) ----
#pragma unroll
        for (int s = 0; s < 2; ++s) {
            if (s >= ns) break;
            const int row = s * 16 + nl;
#pragma unroll
            for (int j = 0; j < 2; ++j) {
                half4 hh4, hl4;
#pragma unroll
                for (int r = 0; r < 4; ++r) {
                    float x = d1[s][j][r];
                    x = x > 0.f ? x : 0.01f * x;
                    _Float16 a = (_Float16)x;
                    hh4[r] = a; hl4[r] = (_Float16)(x - (float)a);
                }
                const int cf = (2 * w + j) * 16 + q * 4;
                *(half4*)&Hsh[row][cf] = hh4;
                *(half4*)&Hsl[row][cf] = hl4;
            }
        }
        __syncthreads();

        // ---- GEMM2': O^T = W2^T @ H^T, split f16 ----
        f32x4 d2[2];
#pragma unroll
        for (int s = 0; s < 2; ++s)
            d2[s] = *(const f32x4*)(b2 + w * 16 + q * 4);

#pragma unroll
        for (int kb = 0; kb < 8; ++kb) {
#pragma unroll
            for (int s = 0; s < 2; ++s) {
                if (s >= ns) break;
                const int row = s * 16 + nl;
                half8 hh = *(const half8*)&Hsh[row][kb * 32 + q * 8];
                half8 hl = *(const half8*)&Hsl[row][kb * 32 + q * 8];
                d2[s] = __builtin_amdgcn_mfma_f32_16x16x32_f16(w2h[kb], hh, d2[s], 0, 0, 0);
                d2[s] = __builtin_amdgcn_mfma_f32_16x16x32_f16(w2h[kb], hl, d2[s], 0, 0, 0);
                d2[s] = __builtin_amdgcn_mfma_f32_16x16x32_f16(w2l[kb], hh, d2[s], 0, 0, 0);
            }
        }

        // ---- epilogue 2: lrelu; O to parity-split LDS + global for row<n ----
#pragma unroll
        for (int s = 0; s < 2; ++s) {
            if (s >= ns) break;
            const int row = s * 16 + nl;
            f32x4 o;
#pragma unroll
            for (int r = 0; r < 4; ++r) { float x = d2[s][r]; o[r] = x > 0.f ? x : 0.01f * x; }
            half4 oh4, ol4;
#pragma unroll
            for (int r = 0; r < 4; ++r) {
                _Float16 a = (_Float16)o[r];
                oh4[r] = a; ol4[r] = (_Float16)(o[r] - (float)a);
            }
            const int cf = w * 16 + q * 4;
            *(half4*)&Obh[row & 1][row >> 1][cf] = oh4;
            *(half4*)&Obl[row & 1][row >> 1][cf] = ol4;
            if (row < n)
                *(f32x4*)(embs + (size_t)(p0 + row) * EMB + cf) = o;
        }
        __syncthreads();
    }
}

// ---------------------------------------------------------------------------
extern "C" void kernel_launch(void* const* d_in, const int* in_sizes, int n_in,
                              void* d_out, int out_size, void* d_ws, size_t ws_size,
                              hipStream_t stream)
{
    const float* lv = (const float*)d_in[0];
    const float* We = (const float*)d_in[1];
    const float* be = (const float*)d_in[2];
    const float* W1 = (const float*)d_in[3];
    const float* b1 = (const float*)d_in[4];
    const float* W2 = (const float*)d_in[5];
    const float* b2 = (const float*)d_in[6];
    float* embs = (float*)d_out;

    _Float16* W1f = (_Float16*)d_ws;            // 65536 f16 = 128 KB
    _Float16* W2f = W1f + 65536;                // 32768 f16 =  64 KB
    _Float16* W1l = W2f + 32768;                // 65536 f16 = 128 KB
    _Float16* W2l = W1l + 65536;                // 32768 f16 =  64 KB
    _Float16* Wef = W2l + 32768;                //  4096 f16 =   8 KB
    _Float16* Wel = Wef + 4096;                 //  4096 f16 =   8 KB  (400 KB)

    prep_weights<<<50, 256, 0, stream>>>(W1, W2, We, W1f, W2f, W1l, W2l, Wef, Wel);
    tree_ladder<<<512, 512, 0, stream>>>(W1f, W2f, Wef, Wel, lv, be, b1, b2, embs);
    mid_ladder<<<1, 512, 0, stream>>>(W1f, W2f, b1, b2, embs);
    tail_levels<<<1, 512, 0, stream>>>(W1f, W1l, W2f, W2l, b1, b2, embs);
}